// Round 11
// baseline (50670.221 us; speedup 1.0000x reference)
//
#include <hip/hip_runtime.h>
#include <math.h>

#define NIMG 12
#define NN 512
#define NPIX (NN * NN)
#define WAVES 16

// ---------------------------------------------------------------------------
// K1: blur = sqrt(bx^2+by^2), latent = sqrt(lx^2+ly^2) — np-exact f32 op
// order (no fma contraction, correctly-rounded f32 sqrt via f64 sqrt).
// ---------------------------------------------------------------------------
__global__ __launch_bounds__(256) void mag_kernel(
    const float* __restrict__ bx, const float* __restrict__ by,
    const float* __restrict__ lx, const float* __restrict__ ly,
    float* __restrict__ blur, float* __restrict__ lat)
{
  const int i = blockIdx.x * 256 + threadIdx.x;
  {
    const float a = bx[i], b = by[i];
    const float s = __fadd_rn(__fmul_rn(a, a), __fmul_rn(b, b));
    blur[i] = (float)sqrt((double)s);
  }
  {
    const float a = lx[i], b = ly[i];
    const float s = __fadd_rn(__fmul_rn(a, a), __fmul_rn(b, b));
    lat[i] = (float)sqrt((double)s);
  }
}

// ---------------------------------------------------------------------------
// In-register 512-pt radix-2 DIT FFT, SINGLE PRECISION internal arithmetic
// (f32 butterflies, f32 twiddles rounded from exact f64 values, no FMA
// contraction) — emulating a dtype-preserving CPU port (pocketfft-single /
// torch.fft / scipy.fft on float32). Structure identical to the R5/R9
// f64 version that was verified on-device.
// ---------------------------------------------------------------------------
__device__ __forceinline__ void fft512_wavef(
    float2* __restrict__ W, const int base, const int stride, const int inv,
    const float* __restrict__ twr, const float* __restrict__ twi,
    const int lane)
{
  float vr[8], vi[8];
#pragma unroll
  for (int e = 0; e < 8; ++e) {
    const int p = lane * 8 + e;
    const int q = (int)(__brev((unsigned)p) >> 23);
    const float2 z = W[base + stride * q];
    vr[e] = z.x; vi[e] = z.y;
  }
#pragma unroll
  for (int s = 0; s < 3; ++s) {          // lane-local stages
    const int half = 1 << s;
#pragma unroll
    for (int e = 0; e < 8; ++e) {
      if ((e & half) == 0) {
        const int j = (e & (half - 1)) << (8 - s);
        const float wr = twr[j];
        const float wi = inv ? -twi[j] : twi[j];
        const float br = vr[e + half], bi = vi[e + half];
        const float tr = __fsub_rn(__fmul_rn(wr, br), __fmul_rn(wi, bi));
        const float ti = __fadd_rn(__fmul_rn(wr, bi), __fmul_rn(wi, br));
        vr[e + half] = __fsub_rn(vr[e], tr); vi[e + half] = __fsub_rn(vi[e], ti);
        vr[e] = __fadd_rn(vr[e], tr); vi[e] = __fadd_rn(vi[e], ti);
      }
    }
  }
#pragma unroll
  for (int s = 3; s <= 8; ++s) {         // cross-lane stages
    const int xm = 1 << (s - 3);
    const bool low = (lane & xm) == 0;
#pragma unroll
    for (int e = 0; e < 8; ++e) {
      const float orr = __shfl_xor(vr[e], xm);
      const float oii = __shfl_xor(vi[e], xm);
      const int j = ((((lane & (xm - 1)) << 3) | e)) << (8 - s);
      const float wr = twr[j];
      const float wi = inv ? -twi[j] : twi[j];
      if (low) {
        const float tr = __fsub_rn(__fmul_rn(wr, orr), __fmul_rn(wi, oii));
        const float ti = __fadd_rn(__fmul_rn(wr, oii), __fmul_rn(wi, orr));
        vr[e] = __fadd_rn(vr[e], tr); vi[e] = __fadd_rn(vi[e], ti);
      } else {
        const float tr = __fsub_rn(__fmul_rn(wr, vr[e]), __fmul_rn(wi, vi[e]));
        const float ti = __fadd_rn(__fmul_rn(wr, vi[e]), __fmul_rn(wi, vr[e]));
        vr[e] = __fsub_rn(orr, tr); vi[e] = __fsub_rn(oii, ti);
      }
    }
  }
  if (inv) {
    const float sc = 1.0f / 512.0f;      // exact power of two
#pragma unroll
    for (int e = 0; e < 8; ++e) {
      vr[e] = __fmul_rn(vr[e], sc); vi[e] = __fmul_rn(vi[e], sc);
    }
  }
#pragma unroll
  for (int e = 0; e < 8; ++e)
    W[base + stride * (lane * 8 + e)] = make_float2(vr[e], vi[e]);
}

// ---------------------------------------------------------------------------
// numpy pairwise_sum for contiguous float32, n = 961, NON-RECURSIVE (R9-ran).
// ---------------------------------------------------------------------------
__device__ __forceinline__ float np_pw_base(const float* a, int n)
{
  float r0 = a[0], r1 = a[1], r2 = a[2], r3 = a[3];
  float r4 = a[4], r5 = a[5], r6 = a[6], r7 = a[7];
  int i = 8;
  const int lim = n - (n & 7);
  for (; i < lim; i += 8) {
    r0 = __fadd_rn(r0, a[i + 0]); r1 = __fadd_rn(r1, a[i + 1]);
    r2 = __fadd_rn(r2, a[i + 2]); r3 = __fadd_rn(r3, a[i + 3]);
    r4 = __fadd_rn(r4, a[i + 4]); r5 = __fadd_rn(r5, a[i + 5]);
    r6 = __fadd_rn(r6, a[i + 6]); r7 = __fadd_rn(r7, a[i + 7]);
  }
  float res = __fadd_rn(
      __fadd_rn(__fadd_rn(r0, r1), __fadd_rn(r2, r3)),
      __fadd_rn(__fadd_rn(r4, r5), __fadd_rn(r6, r7)));
  for (; i < n; ++i) res = __fadd_rn(res, a[i]);
  return res;
}

__device__ __forceinline__ float np_pairwise961(const float* a)
{
  const float b0 = np_pw_base(a,       120);
  const float b1 = np_pw_base(a + 120, 120);
  const float b2 = np_pw_base(a + 240, 120);
  const float b3 = np_pw_base(a + 360, 120);
  const float b4 = np_pw_base(a + 480, 120);
  const float b5 = np_pw_base(a + 600, 120);
  const float b6 = np_pw_base(a + 720, 120);
  const float b7 = np_pw_base(a + 840, 121);
  const float L = __fadd_rn(__fadd_rn(b0, b1), __fadd_rn(b2, b3));
  const float R = __fadd_rn(__fadd_rn(b4, b5), __fadd_rn(b6, b7));
  return __fadd_rn(L, R);
}

// ---------------------------------------------------------------------------
// K2: FULLY-f32 pipeline (f32-internal FFTs), R9's proven skeleton:
// one block (1024 thr) per image, full 512-line FFT passes.
//  latent_f = fft2_f32(lat) -> LF;  FT per-use = f32(lr^2)+f32(li^2)
//  bf = conj(LF)*fft2_f32(blur) (f32 pair arith); b = Re(ifft2_f32(bf))
//  apply: xf = fft2_f32(scatter(p)); literal _mask_imag (f32 stats);
//         FT*xf (f32); y = Re(ifft2_f32)[roll+crop]; Ap = y+p (f32)
//  CG f32, numpy op-order, flat pairwise sums; f32 epilogue.
// ---------------------------------------------------------------------------
__global__ __launch_bounds__(1024) void cgfull_kernel(
    const float* __restrict__ lat, const float* __restrict__ blur,
    float2* __restrict__ latf_g, float2* __restrict__ W_g,
    float* __restrict__ out)
{
  __shared__ float twr[256], twi[256];
  __shared__ float xv[961], rv[961], pv[961], Ap[961], prod[961], bvec[961];
  __shared__ float redf[16], redf2[16];
  __shared__ float scal;
  __shared__ int mflag;

  const int tid  = threadIdx.x;
  const int wave = tid >> 6;
  const int lane = tid & 63;
  const int img  = blockIdx.x;

  float2* __restrict__ W  = W_g    + (size_t)img * NPIX;
  float2* __restrict__ LF = latf_g + (size_t)img * NPIX;
  const float* __restrict__ latp  = lat  + (size_t)img * NPIX;
  const float* __restrict__ blurp = blur + (size_t)img * NPIX;

  for (int k = tid; k < 256; k += 1024) {
    double s, c;
    sincos(-2.0 * M_PI * (double)k / 512.0, &s, &c);
    twr[k] = (float)c; twi[k] = (float)s;   // correctly-rounded f32 twiddles
  }
  __syncthreads();

  // ---- latent_f = fft2_f32(lat) -> LF ----
  for (int i = tid; i < NPIX; i += 1024)
    W[i] = make_float2(latp[i], 0.f);
  __syncthreads();
  for (int r = wave; r < NN; r += WAVES) fft512_wavef(W, r * NN, 1, 0, twr, twi, lane);
  __syncthreads();
  for (int c = wave; c < NN; c += WAVES) fft512_wavef(W, c, NN, 0, twr, twi, lane);
  __syncthreads();
  for (int i = tid; i < NPIX; i += 1024) LF[i] = W[i];
  __syncthreads();

  // ---- bf = conj(LF) * fft2_f32(blur) (f32 pair arith); b = Re(ifft2_f32) --
  for (int i = tid; i < NPIX; i += 1024)
    W[i] = make_float2(blurp[i], 0.f);
  __syncthreads();
  for (int r = wave; r < NN; r += WAVES) fft512_wavef(W, r * NN, 1, 0, twr, twi, lane);
  __syncthreads();
  for (int c = wave; c < NN; c += WAVES) fft512_wavef(W, c, NN, 0, twr, twi, lane);
  __syncthreads();
  for (int i = tid; i < NPIX; i += 1024) {
    const float br = W[i].x, bi = W[i].y;
    const float2 l = LF[i];
    const float re = __fadd_rn(__fmul_rn(l.x, br), __fmul_rn(l.y, bi));
    const float im = __fsub_rn(__fmul_rn(l.x, bi), __fmul_rn(l.y, br));
    W[i] = make_float2(re, im);
  }
  __syncthreads();
  for (int r = wave; r < NN; r += WAVES) fft512_wavef(W, r * NN, 1, 1, twr, twi, lane);
  __syncthreads();
  for (int c = wave; c < NN; c += WAVES) fft512_wavef(W, c, NN, 1, twr, twi, lane);
  __syncthreads();
  if (tid < 961) {
    const int u = tid / 31, v = tid % 31;
    bvec[tid] = W[((u + 497) & 511) * NN + ((v + 497) & 511)].x;
  }
  __syncthreads();

  const double MTHR =
      961.0 * (log2(31.0) + log2(31.0)) * 1.1920928955078125e-7;
  const bool act = tid < 961;

  auto apply = [&](const float* src) {
    for (int i = tid; i < NPIX; i += 1024) W[i] = make_float2(0.f, 0.f);
    __syncthreads();
    if (act) {                             // pad + roll(-15,-15)
      const int k = tid / 31, l = tid % 31;
      W[((k + 497) & 511) * NN + ((l + 497) & 511)] =
          make_float2(src[tid], 0.f);
    }
    __syncthreads();
    for (int r = wave; r < NN; r += WAVES) fft512_wavef(W, r * NN, 1, 0, twr, twi, lane);
    __syncthreads();
    for (int c = wave; c < NN; c += WAVES) fft512_wavef(W, c, NN, 0, twr, twi, lane);
    __syncthreads();
    // ---- literal _mask_imag stats (f32) ----
    float mi = 0.f, ma = 0.f;
    for (int i = tid; i < NPIX; i += 1024) {
      const float fr = W[i].x, fi = W[i].y;
      mi = fmaxf(mi, fabsf(fi));
      const float ab = (float)sqrt(
          (double)__fadd_rn(__fmul_rn(fr, fr), __fmul_rn(fi, fi)));
      ma = fmaxf(ma, ab);
    }
#pragma unroll
    for (int off = 32; off; off >>= 1) {
      mi = fmaxf(mi, __shfl_xor(mi, off));
      ma = fmaxf(ma, __shfl_xor(ma, off));
    }
    if (lane == 0) { redf[wave] = mi; redf2[wave] = ma; }
    __syncthreads();
    if (tid == 0) {
      float m1 = 0.f, m2 = 0.f;
      for (int w = 0; w < 16; ++w) {
        m1 = fmaxf(m1, redf[w]); m2 = fmaxf(m2, redf2[w]);
      }
      mflag = ((double)__fdiv_rn(m1, m2) <= MTHR) ? 1 : 0;
    }
    __syncthreads();
    const bool fire = (mflag != 0);
    // ---- latent_ft * xf in f32 (FT from LF; FT imag = +0 exactly) ----
    for (int i = tid; i < NPIX; i += 1024) {
      const float fr = W[i].x;
      const float fi = fire ? 0.f : W[i].y;
      const float2 l = LF[i];
      const float F = __fadd_rn(__fmul_rn(l.x, l.x), __fmul_rn(l.y, l.y));
      W[i] = make_float2(__fmul_rn(F, fr), __fmul_rn(F, fi));
    }
    __syncthreads();
    for (int r = wave; r < NN; r += WAVES) fft512_wavef(W, r * NN, 1, 1, twr, twi, lane);
    __syncthreads();
    for (int c = wave; c < NN; c += WAVES) fft512_wavef(W, c, NN, 1, twr, twi, lane);
    __syncthreads();
    if (act) {                             // roll(+15,+15)+crop, Re
      const int u = tid / 31, v = tid % 31;
      const float y = W[((u + 497) & 511) * NN + ((v + 497) & 511)].x;
      Ap[tid] = __fadd_rn(y, src[tid]);
    }
    __syncthreads();
  };

  auto psum = [&]() -> float {
    __syncthreads();
    if (tid == 0) scal = np_pairwise961(prod);
    __syncthreads();
    const float s = scal;
    __syncthreads();
    return s;
  };
  auto pmax = [&](float v) -> float {
#pragma unroll
    for (int off = 32; off; off >>= 1) v = fmaxf(v, __shfl_xor(v, off));
    if (lane == 0) redf[wave] = v;
    __syncthreads();
    if (tid == 0) {
      float s = redf[0];
      for (int w = 1; w < 16; ++w) s = fmaxf(s, redf[w]);
      scal = s;
    }
    __syncthreads();
    const float s = scal;
    __syncthreads();
    return s;
  };

  if (act) xv[tid] = (float)(1.0 / 961.0);
  __syncthreads();

  apply(xv);                               // A x0

  if (act) {
    const float r0 = __fsub_rn(bvec[tid], Ap[tid]);
    rv[tid] = r0; pv[tid] = r0;
    prod[tid] = __fmul_rn(r0, r0);
  }
  float rsold = psum();

  for (int it = 0; it < 10; ++it) {
    apply(pv);
    if (act) prod[tid] = __fmul_rn(pv[tid], Ap[tid]);
    const float pAp   = psum();
    const float alpha = rsold / pAp;
    if (act) {
      xv[tid] = __fadd_rn(xv[tid], __fmul_rn(alpha, pv[tid]));
      const float nr = __fsub_rn(rv[tid], __fmul_rn(alpha, Ap[tid]));
      rv[tid] = nr;
      prod[tid] = __fmul_rn(nr, nr);
    }
    const float rsnew = psum();
    const float beta  = rsnew / rsold;
    if (act) pv[tid] = __fadd_rn(rv[tid], __fmul_rn(beta, pv[tid]));
    rsold = rsnew;
  }

  // ---- epilogue: 5% threshold, clamp, normalize (f32) ----
  const float maxv = pmax(act ? xv[tid] : -3.4e38f);
  const float thrf = __fmul_rn(0.05f, maxv);
  float vvv = act ? xv[tid] : 0.f;
  if (vvv < thrf) vvv = 0.f;
  if (vvv < 0.f)  vvv = 0.f;
  if (act) prod[tid] = vvv;
  const float ssum = psum();
  if (act) out[(size_t)img * 961 + tid] = vvv / ssum;
}

// ---------------------------------------------------------------------------
extern "C" void kernel_launch(void* const* d_in, const int* in_sizes, int n_in,
                              void* d_out, int out_size, void* d_ws, size_t ws_size,
                              hipStream_t stream)
{
  const float* bx = (const float*)d_in[0];   // blurx
  const float* by = (const float*)d_in[1];   // blury
  const float* lx = (const float*)d_in[2];   // latentx
  const float* ly = (const float*)d_in[3];   // latenty

  // ws layout (75.5 MB, under the proven-safe 100.7 MB):
  //   W    : 12 * NPIX float2   25.17 MB
  //   LF   : 12 * NPIX float2   25.17 MB
  //   lat  : 12 * NPIX float    12.58 MB
  //   blur : 12 * NPIX float    12.58 MB
  float* ws = (float*)d_ws;
  float2* W    = (float2*)ws;
  float2* latf = (float2*)(ws + NIMG * NPIX * 2);
  float*  lat  = ws + NIMG * NPIX * 4;
  float*  blur = lat + NIMG * NPIX;
  float*  out  = (float*)d_out;

  mag_kernel<<<NIMG * NPIX / 256, 256, 0, stream>>>(bx, by, lx, ly, blur, lat);
  cgfull_kernel<<<NIMG, 1024, 0, stream>>>(lat, blur, latf, W, out);
}

// Round 12
// 1928.853 us; speedup vs baseline: 26.2696x; 26.2696x over previous
//
#include <hip/hip_runtime.h>
#include <math.h>

#define NIMG 12
#define NN 512
#define NPIX (NN * NN)   // 2^18

// ---------------------------------------------------------------------------
// In-register 512-pt radix-2 DIT FFT, f32 internal (VERBATIM from R11 — the
// arithmetic is frozen: it defines the rounding pattern that matches the ref).
// ---------------------------------------------------------------------------
__device__ __forceinline__ void fft512_wavef(
    float2* __restrict__ W, const int base, const int stride, const int inv,
    const float* __restrict__ twr, const float* __restrict__ twi,
    const int lane)
{
  float vr[8], vi[8];
#pragma unroll
  for (int e = 0; e < 8; ++e) {
    const int p = lane * 8 + e;
    const int q = (int)(__brev((unsigned)p) >> 23);
    const float2 z = W[base + stride * q];
    vr[e] = z.x; vi[e] = z.y;
  }
#pragma unroll
  for (int s = 0; s < 3; ++s) {
    const int half = 1 << s;
#pragma unroll
    for (int e = 0; e < 8; ++e) {
      if ((e & half) == 0) {
        const int j = (e & (half - 1)) << (8 - s);
        const float wr = twr[j];
        const float wi = inv ? -twi[j] : twi[j];
        const float br = vr[e + half], bi = vi[e + half];
        const float tr = __fsub_rn(__fmul_rn(wr, br), __fmul_rn(wi, bi));
        const float ti = __fadd_rn(__fmul_rn(wr, bi), __fmul_rn(wi, br));
        vr[e + half] = __fsub_rn(vr[e], tr); vi[e + half] = __fsub_rn(vi[e], ti);
        vr[e] = __fadd_rn(vr[e], tr); vi[e] = __fadd_rn(vi[e], ti);
      }
    }
  }
#pragma unroll
  for (int s = 3; s <= 8; ++s) {
    const int xm = 1 << (s - 3);
    const bool low = (lane & xm) == 0;
#pragma unroll
    for (int e = 0; e < 8; ++e) {
      const float orr = __shfl_xor(vr[e], xm);
      const float oii = __shfl_xor(vi[e], xm);
      const int j = ((((lane & (xm - 1)) << 3) | e)) << (8 - s);
      const float wr = twr[j];
      const float wi = inv ? -twi[j] : twi[j];
      if (low) {
        const float tr = __fsub_rn(__fmul_rn(wr, orr), __fmul_rn(wi, oii));
        const float ti = __fadd_rn(__fmul_rn(wr, oii), __fmul_rn(wi, orr));
        vr[e] = __fadd_rn(vr[e], tr); vi[e] = __fadd_rn(vi[e], ti);
      } else {
        const float tr = __fsub_rn(__fmul_rn(wr, vr[e]), __fmul_rn(wi, vi[e]));
        const float ti = __fadd_rn(__fmul_rn(wr, vi[e]), __fmul_rn(wi, vr[e]));
        vr[e] = __fsub_rn(orr, tr); vi[e] = __fsub_rn(oii, ti);
      }
    }
  }
  if (inv) {
    const float sc = 1.0f / 512.0f;
#pragma unroll
    for (int e = 0; e < 8; ++e) {
      vr[e] = __fmul_rn(vr[e], sc); vi[e] = __fmul_rn(vi[e], sc);
    }
  }
#pragma unroll
  for (int e = 0; e < 8; ++e)
    W[base + stride * (lane * 8 + e)] = make_float2(vr[e], vi[e]);
}

// ---------------------------------------------------------------------------
// numpy pairwise_sum f32, n=961, non-recursive (verbatim from R11).
// ---------------------------------------------------------------------------
__device__ __forceinline__ float np_pw_base(const float* a, int n)
{
  float r0 = a[0], r1 = a[1], r2 = a[2], r3 = a[3];
  float r4 = a[4], r5 = a[5], r6 = a[6], r7 = a[7];
  int i = 8;
  const int lim = n - (n & 7);
  for (; i < lim; i += 8) {
    r0 = __fadd_rn(r0, a[i + 0]); r1 = __fadd_rn(r1, a[i + 1]);
    r2 = __fadd_rn(r2, a[i + 2]); r3 = __fadd_rn(r3, a[i + 3]);
    r4 = __fadd_rn(r4, a[i + 4]); r5 = __fadd_rn(r5, a[i + 5]);
    r6 = __fadd_rn(r6, a[i + 6]); r7 = __fadd_rn(r7, a[i + 7]);
  }
  float res = __fadd_rn(
      __fadd_rn(__fadd_rn(r0, r1), __fadd_rn(r2, r3)),
      __fadd_rn(__fadd_rn(r4, r5), __fadd_rn(r6, r7)));
  for (; i < n; ++i) res = __fadd_rn(res, a[i]);
  return res;
}

__device__ __forceinline__ float np_pairwise961(const float* a)
{
  const float b0 = np_pw_base(a,       120);
  const float b1 = np_pw_base(a + 120, 120);
  const float b2 = np_pw_base(a + 240, 120);
  const float b3 = np_pw_base(a + 360, 120);
  const float b4 = np_pw_base(a + 480, 120);
  const float b5 = np_pw_base(a + 600, 120);
  const float b6 = np_pw_base(a + 720, 120);
  const float b7 = np_pw_base(a + 840, 121);
  const float L = __fadd_rn(__fadd_rn(b0, b1), __fadd_rn(b2, b3));
  const float R = __fadd_rn(__fadd_rn(b4, b5), __fadd_rn(b6, b7));
  return __fadd_rn(L, R);
}

// ---------------------------------------------------------------------------
__global__ __launch_bounds__(256) void twiddle_kernel(float2* __restrict__ twg)
{
  const int k = threadIdx.x;
  double s, c;
  sincos(-2.0 * M_PI * (double)k / 512.0, &s, &c);
  twg[k] = make_float2((float)c, (float)s);
}

// lat/blur magnitudes fused into complex load (same f32 op-order as R11).
__global__ __launch_bounds__(256) void loadmag_kernel(
    const float* __restrict__ bx, const float* __restrict__ by,
    const float* __restrict__ lx, const float* __restrict__ ly,
    float2* __restrict__ WA, float2* __restrict__ WB)
{
  const int i = blockIdx.x * 256 + threadIdx.x;
  {
    const float a = lx[i], b = ly[i];
    const float s = __fadd_rn(__fmul_rn(a, a), __fmul_rn(b, b));
    WA[i] = make_float2((float)sqrt((double)s), 0.f);
  }
  {
    const float a = bx[i], b = by[i];
    const float s = __fadd_rn(__fmul_rn(a, a), __fmul_rn(b, b));
    WB[i] = make_float2((float)sqrt((double)s), 0.f);
  }
}

// One wave = one 512-pt line FFT. Dual-buffer support for the setup pass.
__global__ __launch_bounds__(256) void fftpass_kernel(
    float2* __restrict__ bufA, float2* __restrict__ bufB,
    int lines_per_buf, int lines_per_img, int sparse, int stride, int inv,
    const float2* __restrict__ twg)
{
  __shared__ float twr[256], twi[256];
  const int tid = threadIdx.x;
  {
    const float2 t = twg[tid];
    twr[tid] = t.x; twi[tid] = t.y;
  }
  __syncthreads();
  int wid = blockIdx.x * 4 + (tid >> 6);
  const int lane = tid & 63;
  float2* buf = bufA;
  if (wid >= lines_per_buf) {
    wid -= lines_per_buf;
    buf = bufB;
    if (buf == nullptr || wid >= lines_per_buf) return;
  }
  const int img = wid / lines_per_img;
  const int s = wid - img * lines_per_img;
  const int line = sparse ? ((497 + s) & 511) : s;
  const int base = img * NPIX + (stride == 1 ? line * NN : line);
  fft512_wavef(buf, base, stride, inv, twr, twi, lane);
}

// bf = conj(WA) * WB  (c64 product in f32 pair arithmetic)
__global__ __launch_bounds__(256) void product_kernel(
    const float2* __restrict__ WA, float2* __restrict__ WB)
{
  const int i = blockIdx.x * 256 + threadIdx.x;
  const float2 l = WA[i], b = WB[i];
  const float re = __fadd_rn(__fmul_rn(l.x, b.x), __fmul_rn(l.y, b.y));
  const float im = __fsub_rn(__fmul_rn(l.x, b.y), __fmul_rn(l.y, b.x));
  WB[i] = make_float2(re, im);
}

__global__ __launch_bounds__(256) void initb_kernel(
    const float2* __restrict__ WB, float* __restrict__ bvec,
    float* __restrict__ xv)
{
  const int t = blockIdx.x * 256 + threadIdx.x;
  if (t >= NIMG * 961) return;
  const int img = t / 961, r = t % 961;
  const int u = r / 31, v = r % 31;
  bvec[t] = WB[img * NPIX + ((u + 497) & 511) * NN + ((v + 497) & 511)].x;
  xv[t] = (float)(1.0 / 961.0);
}

// A1: WB = pad+roll scatter of src; zero the mask-stat accumulators.
__global__ __launch_bounds__(256) void scatter_kernel(
    const float* __restrict__ src, float2* __restrict__ WB,
    unsigned* __restrict__ stats)
{
  const int i = blockIdx.x * 256 + threadIdx.x;
  if (i < 24) stats[i] = 0u;
  const int img = i >> 18;
  const int p = i & (NPIX - 1);
  const int row = p >> 9, col = p & 511;
  const int k = (row + 15) & 511, l = (col + 15) & 511;
  float v = 0.f;
  if (k < 31 && l < 31) v = src[img * 961 + k * 31 + l];
  WB[i] = make_float2(v, 0.f);
}

// A4: per-image max|Im| and max|z| (exact order-free max via uint atomicMax).
__global__ __launch_bounds__(256) void stats_kernel(
    const float2* __restrict__ WB, unsigned* __restrict__ stats)
{
  __shared__ float smi[4], sma[4];
  const int img = blockIdx.y;
  const float2* __restrict__ W = WB + img * NPIX;
  float mi = 0.f, ma = 0.f;
  for (int i = blockIdx.x * 256 + threadIdx.x; i < NPIX; i += gridDim.x * 256) {
    const float fr = W[i].x, fi = W[i].y;
    mi = fmaxf(mi, fabsf(fi));
    const float ab = (float)sqrt(
        (double)__fadd_rn(__fmul_rn(fr, fr), __fmul_rn(fi, fi)));
    ma = fmaxf(ma, ab);
  }
#pragma unroll
  for (int off = 32; off; off >>= 1) {
    mi = fmaxf(mi, __shfl_xor(mi, off));
    ma = fmaxf(ma, __shfl_xor(ma, off));
  }
  const int wave = threadIdx.x >> 6;
  if ((threadIdx.x & 63) == 0) { smi[wave] = mi; sma[wave] = ma; }
  __syncthreads();
  if (threadIdx.x == 0) {
    mi = fmaxf(fmaxf(smi[0], smi[1]), fmaxf(smi[2], smi[3]));
    ma = fmaxf(fmaxf(sma[0], sma[1]), fmaxf(sma[2], sma[3]));
    atomicMax(&stats[img * 2 + 0], __float_as_uint(mi));
    atomicMax(&stats[img * 2 + 1], __float_as_uint(ma));
  }
}

// A5: WB = FT(WA) * mask(WB)   (literal _mask_imag decision, R11 formula)
__global__ __launch_bounds__(256) void mult_kernel(
    const float2* __restrict__ WA, float2* __restrict__ WB,
    const unsigned* __restrict__ stats)
{
  const int i = blockIdx.x * 256 + threadIdx.x;
  const int img = i >> 18;
  const float m1 = __uint_as_float(stats[img * 2 + 0]);
  const float m2 = __uint_as_float(stats[img * 2 + 1]);
  const double MTHR =
      961.0 * (log2(31.0) + log2(31.0)) * 1.1920928955078125e-7;
  const bool fire = ((double)__fdiv_rn(m1, m2) <= MTHR);
  const float2 l = WA[i], x = WB[i];
  const float fi = fire ? 0.f : x.y;
  const float F = __fadd_rn(__fmul_rn(l.x, l.x), __fmul_rn(l.y, l.y));
  WB[i] = make_float2(__fmul_rn(F, x.x), __fmul_rn(F, fi));
}

// A8 (initial): r0 = b - (y + x0); p = r = r0; prod = r0^2
__global__ __launch_bounds__(256) void cropinit_kernel(
    const float2* __restrict__ WB, const float* __restrict__ src,
    const float* __restrict__ bvec, float* __restrict__ rv,
    float* __restrict__ pv, float* __restrict__ prod)
{
  const int t = blockIdx.x * 256 + threadIdx.x;
  if (t >= NIMG * 961) return;
  const int img = t / 961, r = t % 961;
  const int u = r / 31, v = r % 31;
  const float y = WB[img * NPIX + ((u + 497) & 511) * NN + ((v + 497) & 511)].x;
  const float Ap = __fadd_rn(y, src[t]);
  const float r0 = __fsub_rn(bvec[t], Ap);
  rv[t] = r0; pv[t] = r0;
  prod[t] = __fmul_rn(r0, r0);
}

// A8 (iteration): Ap = y + p; prod = p * Ap
__global__ __launch_bounds__(256) void cropiter_kernel(
    const float2* __restrict__ WB, const float* __restrict__ pv,
    float* __restrict__ Ap, float* __restrict__ prod)
{
  const int t = blockIdx.x * 256 + threadIdx.x;
  if (t >= NIMG * 961) return;
  const int img = t / 961, r = t % 961;
  const int u = r / 31, v = r % 31;
  const float y = WB[img * NPIX + ((u + 497) & 511) * NN + ((v + 497) & 511)].x;
  const float a = __fadd_rn(y, pv[t]);
  Ap[t] = a;
  prod[t] = __fmul_rn(pv[t], a);
}

// scalar reduction: mode 0: rsold=s ; 1: alpha=rsold/s ; 2: beta=s/rsold, rsold=s
__global__ __launch_bounds__(256) void sum_kernel(
    const float* __restrict__ prod, float* __restrict__ rsold,
    float* __restrict__ ab, int mode)
{
  __shared__ float buf[961];
  const int img = blockIdx.x;
  for (int i = threadIdx.x; i < 961; i += 256) buf[i] = prod[img * 961 + i];
  __syncthreads();
  if (threadIdx.x == 0) {
    const float s = np_pairwise961(buf);
    if (mode == 0) rsold[img] = s;
    else if (mode == 1) ab[img] = rsold[img] / s;
    else { ab[img] = s / rsold[img]; rsold[img] = s; }
  }
}

__global__ __launch_bounds__(256) void updxr_kernel(
    float* __restrict__ xv, float* __restrict__ rv,
    const float* __restrict__ pv, const float* __restrict__ Ap,
    const float* __restrict__ alpha, float* __restrict__ prod)
{
  const int t = blockIdx.x * 256 + threadIdx.x;
  if (t >= NIMG * 961) return;
  const float al = alpha[t / 961];
  xv[t] = __fadd_rn(xv[t], __fmul_rn(al, pv[t]));
  const float nr = __fsub_rn(rv[t], __fmul_rn(al, Ap[t]));
  rv[t] = nr;
  prod[t] = __fmul_rn(nr, nr);
}

__global__ __launch_bounds__(256) void updp_kernel(
    float* __restrict__ pv, const float* __restrict__ rv,
    const float* __restrict__ beta)
{
  const int t = blockIdx.x * 256 + threadIdx.x;
  if (t >= NIMG * 961) return;
  const float be = beta[t / 961];
  pv[t] = __fadd_rn(rv[t], __fmul_rn(be, pv[t]));
}

// epilogue: 5% threshold, clamp, normalize (R11 structure, xv from global)
__global__ __launch_bounds__(1024) void epi_kernel(
    const float* __restrict__ xv, float* __restrict__ out)
{
  __shared__ float redf[16];
  __shared__ float scal;
  __shared__ float buf[961];
  const int tid = threadIdx.x, wave = tid >> 6, lane = tid & 63;
  const int img = blockIdx.x;
  const bool act = tid < 961;
  const float x = act ? xv[img * 961 + tid] : -3.4e38f;
  float v = x;
#pragma unroll
  for (int off = 32; off; off >>= 1) v = fmaxf(v, __shfl_xor(v, off));
  if (lane == 0) redf[wave] = v;
  __syncthreads();
  if (tid == 0) {
    float s = redf[0];
    for (int w = 1; w < 16; ++w) s = fmaxf(s, redf[w]);
    scal = s;
  }
  __syncthreads();
  const float maxv = scal;
  const float thrf = __fmul_rn(0.05f, maxv);
  float vvv = act ? x : 0.f;
  if (vvv < thrf) vvv = 0.f;
  if (vvv < 0.f)  vvv = 0.f;
  if (act) buf[tid] = vvv;
  __syncthreads();
  if (tid == 0) scal = np_pairwise961(buf);
  __syncthreads();
  const float ssum = scal;
  if (act) out[img * 961 + tid] = vvv / ssum;
}

// ---------------------------------------------------------------------------
extern "C" void kernel_launch(void* const* d_in, const int* in_sizes, int n_in,
                              void* d_out, int out_size, void* d_ws, size_t ws_size,
                              hipStream_t stream)
{
  const float* bx = (const float*)d_in[0];
  const float* by = (const float*)d_in[1];
  const float* lx = (const float*)d_in[2];
  const float* ly = (const float*)d_in[3];

  // ws: WA 25.2MB | WB 25.2MB | vectors ~300KB   (total ~50.7 MB)
  float* ws = (float*)d_ws;
  float2* WA = (float2*)ws;                         // latent_f (persistent)
  float2* WB = (float2*)(ws + NIMG * NPIX * 2);     // scratch
  float*  vec  = ws + NIMG * NPIX * 4;
  float*  bvec = vec;                // 12*961
  float*  xv   = bvec + NIMG * 961;
  float*  rv   = xv   + NIMG * 961;
  float*  pv   = rv   + NIMG * 961;
  float*  Ap   = pv   + NIMG * 961;
  float*  prod = Ap   + NIMG * 961;
  float*  rsold = prod + NIMG * 961;  // 12
  float*  alpha = rsold + NIMG;       // 12
  float*  beta  = alpha + NIMG;       // 12
  unsigned* stats = (unsigned*)(beta + NIMG);       // 24
  float2* twg = (float2*)(beta + NIMG + 24);        // 256
  float* out = (float*)d_out;

  const int GP = NIMG * NPIX / 256;   // 12288 pointwise blocks
  const int GF = NIMG * NN / 4;       // 1536 full-pass blocks (6144 lines)
  const int GS = NIMG * 31 / 4 + 1;   // 93+1 -> 94 blocks for 372 sparse lines
  const int GV = (NIMG * 961 + 255) / 256;  // 46

  twiddle_kernel<<<1, 256, 0, stream>>>(twg);
  loadmag_kernel<<<GP, 256, 0, stream>>>(bx, by, lx, ly, WA, WB);
  // fft2 of lat & blur (rows then cols, full)
  fftpass_kernel<<<2 * GF, 256, 0, stream>>>(WA, WB, NIMG * NN, NN, 0, 1, 0, twg);
  fftpass_kernel<<<2 * GF, 256, 0, stream>>>(WA, WB, NIMG * NN, NN, 0, NN, 0, twg);
  product_kernel<<<GP, 256, 0, stream>>>(WA, WB);
  fftpass_kernel<<<GF, 256, 0, stream>>>(WB, nullptr, NIMG * NN, NN, 0, 1, 1, twg);
  fftpass_kernel<<<GS, 256, 0, stream>>>(WB, nullptr, NIMG * 31, 31, 1, NN, 1, twg);
  initb_kernel<<<GV, 256, 0, stream>>>(WB, bvec, xv);

  // one apply: scatter, sparse fwd rows, full fwd cols, stats, mult,
  //            inv rows full, inv cols sparse
  auto apply = [&](const float* src) {
    scatter_kernel<<<GP, 256, 0, stream>>>(src, WB, stats);
    fftpass_kernel<<<GS, 256, 0, stream>>>(WB, nullptr, NIMG * 31, 31, 1, 1, 0, twg);
    fftpass_kernel<<<GF, 256, 0, stream>>>(WB, nullptr, NIMG * NN, NN, 0, NN, 0, twg);
    dim3 sg(128, NIMG);
    stats_kernel<<<sg, 256, 0, stream>>>(WB, stats);
    mult_kernel<<<GP, 256, 0, stream>>>(WA, WB, stats);
    fftpass_kernel<<<GF, 256, 0, stream>>>(WB, nullptr, NIMG * NN, NN, 0, 1, 1, twg);
    fftpass_kernel<<<GS, 256, 0, stream>>>(WB, nullptr, NIMG * 31, 31, 1, NN, 1, twg);
  };

  apply(xv);
  cropinit_kernel<<<GV, 256, 0, stream>>>(WB, xv, bvec, rv, pv, prod);
  sum_kernel<<<NIMG, 256, 0, stream>>>(prod, rsold, alpha, 0);

  for (int it = 0; it < 10; ++it) {
    apply(pv);
    cropiter_kernel<<<GV, 256, 0, stream>>>(WB, pv, Ap, prod);
    sum_kernel<<<NIMG, 256, 0, stream>>>(prod, rsold, alpha, 1);
    updxr_kernel<<<GV, 256, 0, stream>>>(xv, rv, pv, Ap, alpha, prod);
    sum_kernel<<<NIMG, 256, 0, stream>>>(prod, rsold, beta, 2);
    updp_kernel<<<GV, 256, 0, stream>>>(pv, rv, beta);
  }

  epi_kernel<<<NIMG, 1024, 0, stream>>>(xv, out);
}

// Round 13
// 1735.132 us; speedup vs baseline: 29.2025x; 1.1116x over previous
//
#include <hip/hip_runtime.h>
#include <math.h>

#define NIMG 12
#define NN 512
#define NPIX (NN * NN)

__device__ __forceinline__ int brev9(int p) {
  return (int)(__brev((unsigned)p) >> 23);
}

// ---------------------------------------------------------------------------
// FROZEN 512-pt radix-2 DIT FFT core (register-resident), f32, no FMA.
// Arithmetic bit-identical to R11/R12's fft512_wavef; caller does the
// bit-reversed load and natural-order store.
// ---------------------------------------------------------------------------
__device__ __forceinline__ void fft512_core(
    float vr[8], float vi[8], const int inv,
    const float* __restrict__ twr, const float* __restrict__ twi,
    const int lane)
{
#pragma unroll
  for (int s = 0; s < 3; ++s) {
    const int half = 1 << s;
#pragma unroll
    for (int e = 0; e < 8; ++e) {
      if ((e & half) == 0) {
        const int j = (e & (half - 1)) << (8 - s);
        const float wr = twr[j];
        const float wi = inv ? -twi[j] : twi[j];
        const float br = vr[e + half], bi = vi[e + half];
        const float tr = __fsub_rn(__fmul_rn(wr, br), __fmul_rn(wi, bi));
        const float ti = __fadd_rn(__fmul_rn(wr, bi), __fmul_rn(wi, br));
        vr[e + half] = __fsub_rn(vr[e], tr); vi[e + half] = __fsub_rn(vi[e], ti);
        vr[e] = __fadd_rn(vr[e], tr); vi[e] = __fadd_rn(vi[e], ti);
      }
    }
  }
#pragma unroll
  for (int s = 3; s <= 8; ++s) {
    const int xm = 1 << (s - 3);
    const bool low = (lane & xm) == 0;
#pragma unroll
    for (int e = 0; e < 8; ++e) {
      const float orr = __shfl_xor(vr[e], xm);
      const float oii = __shfl_xor(vi[e], xm);
      const int j = ((((lane & (xm - 1)) << 3) | e)) << (8 - s);
      const float wr = twr[j];
      const float wi = inv ? -twi[j] : twi[j];
      if (low) {
        const float tr = __fsub_rn(__fmul_rn(wr, orr), __fmul_rn(wi, oii));
        const float ti = __fadd_rn(__fmul_rn(wr, oii), __fmul_rn(wi, orr));
        vr[e] = __fadd_rn(vr[e], tr); vi[e] = __fadd_rn(vi[e], ti);
      } else {
        const float tr = __fsub_rn(__fmul_rn(wr, vr[e]), __fmul_rn(wi, vi[e]));
        const float ti = __fadd_rn(__fmul_rn(wr, vi[e]), __fmul_rn(wi, vr[e]));
        vr[e] = __fsub_rn(orr, tr); vi[e] = __fsub_rn(oii, ti);
      }
    }
  }
  if (inv) {
    const float sc = 1.0f / 512.0f;
#pragma unroll
    for (int e = 0; e < 8; ++e) {
      vr[e] = __fmul_rn(vr[e], sc); vi[e] = __fmul_rn(vi[e], sc);
    }
  }
}

// ---------------------------------------------------------------------------
// numpy pairwise_sum f32 n=961 (frozen tree). 8-segment base blocks.
// ---------------------------------------------------------------------------
__device__ __forceinline__ float np_pw_base(const float* a, int n)
{
  float r0 = a[0], r1 = a[1], r2 = a[2], r3 = a[3];
  float r4 = a[4], r5 = a[5], r6 = a[6], r7 = a[7];
  int i = 8;
  const int lim = n - (n & 7);
  for (; i < lim; i += 8) {
    r0 = __fadd_rn(r0, a[i + 0]); r1 = __fadd_rn(r1, a[i + 1]);
    r2 = __fadd_rn(r2, a[i + 2]); r3 = __fadd_rn(r3, a[i + 3]);
    r4 = __fadd_rn(r4, a[i + 4]); r5 = __fadd_rn(r5, a[i + 5]);
    r6 = __fadd_rn(r6, a[i + 6]); r7 = __fadd_rn(r7, a[i + 7]);
  }
  float res = __fadd_rn(
      __fadd_rn(__fadd_rn(r0, r1), __fadd_rn(r2, r3)),
      __fadd_rn(__fadd_rn(r4, r5), __fadd_rn(r6, r7)));
  for (; i < n; ++i) res = __fadd_rn(res, a[i]);
  return res;
}

// ---------------------------------------------------------------------------
__global__ __launch_bounds__(256) void twiddle_kernel(float2* __restrict__ twg)
{
  const int k = threadIdx.x;
  double s, c;
  sincos(-2.0 * M_PI * (double)k / 512.0, &s, &c);
  twg[k] = make_float2((float)c, (float)s);
}

// magnitudes -> complex planes: B2 = latent (row-major), B1 = blur (row-major)
__global__ __launch_bounds__(256) void loadmag_kernel(
    const float* __restrict__ bx, const float* __restrict__ by,
    const float* __restrict__ lx, const float* __restrict__ ly,
    float2* __restrict__ B2, float2* __restrict__ B1)
{
  const int i = blockIdx.x * 256 + threadIdx.x;
  {
    const float a = lx[i], b = ly[i];
    const float s = __fadd_rn(__fmul_rn(a, a), __fmul_rn(b, b));
    B2[i] = make_float2((float)sqrt((double)s), 0.f);
  }
  {
    const float a = bx[i], b = by[i];
    const float s = __fadd_rn(__fmul_rn(a, a), __fmul_rn(b, b));
    B1[i] = make_float2((float)sqrt((double)s), 0.f);
  }
}

// dense forward ROW pass, dual buffer, in-place. wave = one row.
__global__ __launch_bounds__(256) void rowfft_kernel(
    float2* __restrict__ A, float2* __restrict__ B,
    const float2* __restrict__ twg)
{
  __shared__ float twr[256], twi[256];
  { const float2 t = twg[threadIdx.x]; twr[threadIdx.x] = t.x; twi[threadIdx.x] = t.y; }
  __syncthreads();
  int wid = blockIdx.x * 4 + (threadIdx.x >> 6);
  const int lane = threadIdx.x & 63;
  float2* buf = A;
  if (wid >= NIMG * NN) { wid -= NIMG * NN; buf = B; }
  const int base = (wid >> 9) * NPIX + (wid & 511) * NN;
  float vr[8], vi[8];
#pragma unroll
  for (int e = 0; e < 8; ++e) {
    const float2 z = buf[base + brev9(lane * 8 + e)];
    vr[e] = z.x; vi[e] = z.y;
  }
  fft512_core(vr, vi, 0, twr, twi, lane);
#pragma unroll
  for (int e = 0; e < 8; ++e)
    buf[base + lane * 8 + e] = make_float2(vr[e], vi[e]);
}

// dense forward COL pass for WA (B2), IN-PLACE [row][col], LDS-tiled.
// block = 4 columns of one image; 4 waves, one col FFT each.
__global__ __launch_bounds__(256) void colA_kernel(
    float2* __restrict__ B2, const float2* __restrict__ twg)
{
  __shared__ float twr[256], twi[256];
  __shared__ float2 ld[4][520];
  { const float2 t = twg[threadIdx.x]; twr[threadIdx.x] = t.x; twi[threadIdx.x] = t.y; }
  const int img = blockIdx.x >> 7;
  const int c0  = (blockIdx.x & 127) * 4;
  const int tid = threadIdx.x;
  float2* __restrict__ base = B2 + img * NPIX;
  for (int it = 0; it < 8; ++it) {
    const int idx = it * 256 + tid;
    ld[idx & 3][idx >> 2] = base[(idx >> 2) * NN + c0 + (idx & 3)];
  }
  __syncthreads();
  const int w = tid >> 6, lane = tid & 63;
  float vr[8], vi[8];
#pragma unroll
  for (int e = 0; e < 8; ++e) {
    const float2 z = ld[w][brev9(lane * 8 + e)];
    vr[e] = z.x; vi[e] = z.y;
  }
  fft512_core(vr, vi, 0, twr, twi, lane);
#pragma unroll
  for (int e = 0; e < 8; ++e) ld[w][lane * 8 + e] = make_float2(vr[e], vi[e]);
  __syncthreads();
  for (int it = 0; it < 8; ++it) {
    const int idx = it * 256 + tid;
    base[(idx >> 2) * NN + c0 + (idx & 3)] = ld[idx & 3][idx >> 2];
  }
}

// dense forward COL pass for blur: B1 [row][col] -> B3 TRANSPOSED [col][row].
__global__ __launch_bounds__(256) void colB_kernel(
    const float2* __restrict__ B1, float2* __restrict__ B3,
    const float2* __restrict__ twg)
{
  __shared__ float twr[256], twi[256];
  __shared__ float2 ld[4][520];
  { const float2 t = twg[threadIdx.x]; twr[threadIdx.x] = t.x; twi[threadIdx.x] = t.y; }
  const int img = blockIdx.x >> 7;
  const int c0  = (blockIdx.x & 127) * 4;
  const int tid = threadIdx.x;
  const float2* __restrict__ in = B1 + img * NPIX;
  for (int it = 0; it < 8; ++it) {
    const int idx = it * 256 + tid;
    ld[idx & 3][idx >> 2] = in[(idx >> 2) * NN + c0 + (idx & 3)];
  }
  __syncthreads();
  const int w = tid >> 6, lane = tid & 63;
  const int c = c0 + w;
  float vr[8], vi[8];
#pragma unroll
  for (int e = 0; e < 8; ++e) {
    const float2 z = ld[w][brev9(lane * 8 + e)];
    vr[e] = z.x; vi[e] = z.y;
  }
  fft512_core(vr, vi, 0, twr, twi, lane);
  float2* __restrict__ out = B3 + img * NPIX + c * NN + lane * 8;
#pragma unroll
  for (int e = 0; e < 8; ++e) out[e] = make_float2(vr[e], vi[e]);
}

// APPLY col-FFT: sparse input from R[img][31][512]; output X=B3 [col][row];
// fused _mask_imag stats (order-free max, atomicMax). block = 4 cols.
__global__ __launch_bounds__(256) void kb_kernel(
    const float2* __restrict__ R, float2* __restrict__ B3,
    unsigned* __restrict__ stats, const float2* __restrict__ twg)
{
  __shared__ float twr[256], twi[256];
  __shared__ float smi[4], sma[4];
  { const float2 t = twg[threadIdx.x]; twr[threadIdx.x] = t.x; twi[threadIdx.x] = t.y; }
  __syncthreads();
  const int img = blockIdx.x >> 7;
  const int c   = (blockIdx.x & 127) * 4 + (threadIdx.x >> 6);
  const int lane = threadIdx.x & 63;
  float vr[8], vi[8];
#pragma unroll
  for (int e = 0; e < 8; ++e) {
    const int q = brev9(lane * 8 + e);
    const int k = (q + 15) & 511;
    if (k < 31) {
      const float2 z = R[(img * 31 + k) * NN + c];
      vr[e] = z.x; vi[e] = z.y;
    } else { vr[e] = 0.f; vi[e] = 0.f; }
  }
  fft512_core(vr, vi, 0, twr, twi, lane);
  float mi = 0.f, ma = 0.f;
#pragma unroll
  for (int e = 0; e < 8; ++e) {
    mi = fmaxf(mi, fabsf(vi[e]));
    const float ab = (float)sqrt(
        (double)__fadd_rn(__fmul_rn(vr[e], vr[e]), __fmul_rn(vi[e], vi[e])));
    ma = fmaxf(ma, ab);
  }
#pragma unroll
  for (int off = 32; off; off >>= 1) {
    mi = fmaxf(mi, __shfl_xor(mi, off));
    ma = fmaxf(ma, __shfl_xor(ma, off));
  }
  if (lane == 0) { smi[threadIdx.x >> 6] = mi; sma[threadIdx.x >> 6] = ma; }
  float2* __restrict__ out = B3 + img * NPIX + c * NN + lane * 8;
#pragma unroll
  for (int e = 0; e < 8; ++e) out[e] = make_float2(vr[e], vi[e]);
  __syncthreads();
  if (threadIdx.x == 0) {
    mi = fmaxf(fmaxf(smi[0], smi[1]), fmaxf(smi[2], smi[3]));
    ma = fmaxf(fmaxf(sma[0], sma[1]), fmaxf(sma[2], sma[3]));
    atomicMax(&stats[img * 2 + 0], __float_as_uint(mi));
    atomicMax(&stats[img * 2 + 1], __float_as_uint(ma));
  }
}

// product + inverse ROW FFT -> compact Y[img][31][512] (only the 31 needed
// cols). bmode=1: bf = conj(WA)*X (b-path). bmode=0: FT*mask(X) (apply).
// block = 8 rows; X tile staged in LDS (full-line reads of [col][row]).
__global__ __launch_bounds__(256) void kprod_kernel(
    const float2* __restrict__ B3, const float2* __restrict__ B2,
    float2* __restrict__ Y, const unsigned* __restrict__ stats,
    const float2* __restrict__ twg, int bmode)
{
  __shared__ float twr[256], twi[256];
  __shared__ float2 ldx[8][520];
  { const float2 t = twg[threadIdx.x]; twr[threadIdx.x] = t.x; twi[threadIdx.x] = t.y; }
  const int img = blockIdx.x >> 6;
  const int r0  = (blockIdx.x & 63) * 8;
  const int tid = threadIdx.x;
  const float2* __restrict__ X = B3 + img * NPIX;
  for (int it = 0; it < 16; ++it) {
    const int idx = it * 256 + tid;                 // r_l = idx&7, c = idx>>3
    ldx[idx & 7][idx >> 3] = X[(idx >> 3) * NN + r0 + (idx & 7)];
  }
  bool fire = false;
  if (bmode == 0) {
    const float m1 = __uint_as_float(stats[img * 2 + 0]);
    const float m2 = __uint_as_float(stats[img * 2 + 1]);
    const double MTHR =
        961.0 * (log2(31.0) + log2(31.0)) * 1.1920928955078125e-7;
    fire = ((double)__fdiv_rn(m1, m2) <= MTHR);
  }
  __syncthreads();
  const int w = tid >> 6, lane = tid & 63;
  for (int rep = 0; rep < 2; ++rep) {
    const int r_l = w + 4 * rep;
    const int r = r0 + r_l;
    const float2* __restrict__ Lrow = B2 + img * NPIX + r * NN;
    float vr[8], vi[8];
#pragma unroll
    for (int e = 0; e < 8; ++e) {
      const int q = brev9(lane * 8 + e);
      const float2 xb = ldx[r_l][q];
      const float2 l  = Lrow[q];
      if (bmode) {          // conj(latent)*blur  (exact R12 product_kernel ops)
        vr[e] = __fadd_rn(__fmul_rn(l.x, xb.x), __fmul_rn(l.y, xb.y));
        vi[e] = __fsub_rn(__fmul_rn(l.x, xb.y), __fmul_rn(l.y, xb.x));
      } else {              // FT * mask(xf)      (exact R12 mult_kernel ops)
        const float fi = fire ? 0.f : xb.y;
        const float F  = __fadd_rn(__fmul_rn(l.x, l.x), __fmul_rn(l.y, l.y));
        vr[e] = __fmul_rn(F, xb.x);
        vi[e] = __fmul_rn(F, fi);
      }
    }
    fft512_core(vr, vi, 1, twr, twi, lane);
#pragma unroll
    for (int e = 0; e < 8; ++e) {
      const int c2 = lane * 8 + e;
      if (c2 >= 497 || c2 <= 15) {
        const int v = (c2 + 15) & 511;
        Y[(img * 31 + v) * NN + r] = make_float2(vr[e], vi[e]);
      }
    }
  }
}

// Fused CG tail: 31 inverse COL FFTs (from compact Y) -> y; CG scalar math
// (exact R12 op order, exact numpy pairwise tree, 8-thread parallel);
// next apply's 31 forward ROW FFTs -> R; stats zeroing; final epilogue.
// mode: 2 = setup (y->bvec, x0 init), 0 = first apply (r0/p/rsold),
//       1 = iteration. fin: run epilogue instead of next-FFT phase.
__global__ __launch_bounds__(1024) void kcg_kernel(
    const float2* __restrict__ Y, float2* __restrict__ R,
    float* __restrict__ bvec, float* __restrict__ xv,
    float* __restrict__ rv, float* __restrict__ pv,
    float* __restrict__ rsoldg, unsigned* __restrict__ stats,
    const float2* __restrict__ twg, float* __restrict__ out,
    int mode, int fin)
{
  __shared__ float twr[256], twi[256];
  __shared__ float yl[961], pl[961], prodl[961];
  __shared__ float pwl[8], redf[16];
  __shared__ float scal;
  const int tid = threadIdx.x;
  const int wave = tid >> 6, lane = tid & 63;
  const int img = blockIdx.x;
  if (tid < 256) { const float2 t = twg[tid]; twr[tid] = t.x; twi[tid] = t.y; }
  __syncthreads();

  // ---- Phase A: inverse col FFTs on compact Y -> yl[u*31+v] (real part) ----
  for (int rep = 0; rep < 2; ++rep) {
    const int v = wave + 16 * rep;
    if (v < 31) {
      const float2* __restrict__ Yv = Y + (img * 31 + v) * NN;
      float vr[8], vi[8];
#pragma unroll
      for (int e = 0; e < 8; ++e) {
        const float2 z = Yv[brev9(lane * 8 + e)];
        vr[e] = z.x; vi[e] = z.y;
      }
      fft512_core(vr, vi, 1, twr, twi, lane);
#pragma unroll
      for (int e = 0; e < 8; ++e) {
        const int q2 = lane * 8 + e;
        const int u = (q2 + 15) & 511;
        if (u < 31) yl[u * 31 + v] = vr[e];
      }
    }
  }
  __syncthreads();

  const bool act = tid < 961;
  const int g = img * 961 + tid;

  auto pairwise = [&]() -> float {   // exact numpy pairwise tree over prodl
    __syncthreads();
    if (tid < 8) pwl[tid] = np_pw_base(prodl + tid * 120, (tid == 7) ? 121 : 120);
    __syncthreads();
    if (tid == 0) {
      const float L = __fadd_rn(__fadd_rn(pwl[0], pwl[1]), __fadd_rn(pwl[2], pwl[3]));
      const float Rr = __fadd_rn(__fadd_rn(pwl[4], pwl[5]), __fadd_rn(pwl[6], pwl[7]));
      scal = __fadd_rn(L, Rr);
    }
    __syncthreads();
    const float s = scal;
    __syncthreads();
    return s;
  };

  // ---- Phase B: per-mode scalar math (ops copied verbatim from R12) ----
  if (mode == 2) {
    if (act) {
      bvec[g] = yl[tid];
      xv[g] = (float)(1.0 / 961.0);
      pl[tid] = (float)(1.0 / 961.0);
    }
  } else if (mode == 0) {
    if (act) {
      const float Ap = __fadd_rn(yl[tid], xv[g]);
      const float r0 = __fsub_rn(bvec[g], Ap);
      rv[g] = r0; pv[g] = r0; pl[tid] = r0;
      prodl[tid] = __fmul_rn(r0, r0);
    }
    const float s = pairwise();
    if (tid == 0) rsoldg[img] = s;
  } else {
    float p = 0.f, Ap = 0.f, nr = 0.f;
    if (act) {
      p = pv[g];
      Ap = __fadd_rn(yl[tid], p);
      prodl[tid] = __fmul_rn(p, Ap);
    }
    const float pAp = pairwise();
    if (tid == 0) scal = rsoldg[img] / pAp;
    __syncthreads();
    const float alpha = scal;
    __syncthreads();
    if (act) {
      xv[g] = __fadd_rn(xv[g], __fmul_rn(alpha, p));
      nr = __fsub_rn(rv[g], __fmul_rn(alpha, Ap));
      rv[g] = nr;
      prodl[tid] = __fmul_rn(nr, nr);
    }
    const float rsnew = pairwise();
    if (tid == 0) { scal = rsnew / rsoldg[img]; rsoldg[img] = rsnew; }
    __syncthreads();
    const float beta = scal;
    __syncthreads();
    if (act) {
      const float pn = __fadd_rn(nr, __fmul_rn(beta, p));
      pv[g] = pn; pl[tid] = pn;
    }
  }
  if (tid == 0) { stats[img * 2 + 0] = 0u; stats[img * 2 + 1] = 0u; }
  __syncthreads();

  if (fin) {
    // ---- epilogue (exact R12 epi_kernel ops) ----
    const float x = act ? xv[g] : -3.4e38f;
    float v = x;
#pragma unroll
    for (int off = 32; off; off >>= 1) v = fmaxf(v, __shfl_xor(v, off));
    if (lane == 0) redf[wave] = v;
    __syncthreads();
    if (tid == 0) {
      float s = redf[0];
      for (int w2 = 1; w2 < 16; ++w2) s = fmaxf(s, redf[w2]);
      scal = s;
    }
    __syncthreads();
    const float maxv = scal;
    const float thrf = __fmul_rn(0.05f, maxv);
    float vvv = act ? x : 0.f;
    if (vvv < thrf) vvv = 0.f;
    if (vvv < 0.f)  vvv = 0.f;
    if (act) prodl[tid] = vvv;
    const float ssum = pairwise();
    if (act) out[g] = vvv / ssum;
    return;
  }

  // ---- Phase C: forward row FFTs of pl -> R (for the next apply) ----
  for (int rep = 0; rep < 2; ++rep) {
    const int k = wave + 16 * rep;
    if (k < 31) {
      float vr[8], vi[8];
#pragma unroll
      for (int e = 0; e < 8; ++e) {
        const int q = brev9(lane * 8 + e);
        const int l = (q + 15) & 511;
        vr[e] = (l < 31) ? pl[k * 31 + l] : 0.f;
        vi[e] = 0.f;
      }
      fft512_core(vr, vi, 0, twr, twi, lane);
      float2* __restrict__ Rk = R + (img * 31 + k) * NN + lane * 8;
#pragma unroll
      for (int e = 0; e < 8; ++e) Rk[e] = make_float2(vr[e], vi[e]);
    }
  }
}

// ---------------------------------------------------------------------------
extern "C" void kernel_launch(void* const* d_in, const int* in_sizes, int n_in,
                              void* d_out, int out_size, void* d_ws, size_t ws_size,
                              hipStream_t stream)
{
  const float* bx = (const float*)d_in[0];
  const float* by = (const float*)d_in[1];
  const float* lx = (const float*)d_in[2];
  const float* ly = (const float*)d_in[3];

  // ws: B1 25.2 | B2 25.2 | B3 25.2 | R 1.5 | Y 1.5 | vecs (~79 MB total)
  float* ws = (float*)d_ws;
  float2* B1 = (float2*)ws;                       // blur rows (setup temp)
  float2* B2 = B1 + (size_t)NIMG * NPIX;          // latent_f dense [row][col]
  float2* B3 = B2 + (size_t)NIMG * NPIX;          // X dense [col][row]
  float2* R  = B3 + (size_t)NIMG * NPIX;          // compact fwd rows [31][512]
  float2* Y  = R  + (size_t)NIMG * 31 * NN;       // compact inv rows [31][512]
  float*  vec = (float*)(Y + (size_t)NIMG * 31 * NN);
  float*  bvec = vec;
  float*  xv   = bvec + NIMG * 961;
  float*  rv   = xv   + NIMG * 961;
  float*  pv   = rv   + NIMG * 961;
  float*  rsold = pv  + NIMG * 961;               // 12
  unsigned* stats = (unsigned*)(rsold + NIMG);    // 24
  float2* twg = (float2*)(stats + 24);            // 256
  float* out = (float*)d_out;

  twiddle_kernel<<<1, 256, 0, stream>>>(twg);
  loadmag_kernel<<<NIMG * NPIX / 256, 256, 0, stream>>>(bx, by, lx, ly, B2, B1);
  rowfft_kernel<<<2 * NIMG * NN / 4, 256, 0, stream>>>(B2, B1, twg);
  colA_kernel<<<NIMG * 128, 256, 0, stream>>>(B2, twg);
  colB_kernel<<<NIMG * 128, 256, 0, stream>>>(B1, B3, twg);
  kprod_kernel<<<NIMG * 64, 256, 0, stream>>>(B3, B2, Y, stats, twg, 1);
  kcg_kernel<<<NIMG, 1024, 0, stream>>>(Y, R, bvec, xv, rv, pv, rsold, stats,
                                        twg, out, 2, 0);

  for (int a = 0; a < 11; ++a) {
    kb_kernel<<<NIMG * 128, 256, 0, stream>>>(R, B3, stats, twg);
    kprod_kernel<<<NIMG * 64, 256, 0, stream>>>(B3, B2, Y, stats, twg, 0);
    const int mode = (a == 0) ? 0 : 1;
    const int fin  = (a == 10) ? 1 : 0;
    kcg_kernel<<<NIMG, 1024, 0, stream>>>(Y, R, bvec, xv, rv, pv, rsold, stats,
                                          twg, out, mode, fin);
  }
}